// Round 1
// baseline (802.454 us; speedup 1.0000x reference)
//
#include <hip/hip_runtime.h>

__device__ __forceinline__ float lr(float x, float s) { return x >= 0.f ? x : s * x; }

// ---------------- CSR build (by destination), reused for all 3 layers ----------------
__global__ __launch_bounds__(256) void k_init_cnt(int* __restrict__ cnt, int n) {
  int i = blockIdx.x * 256 + threadIdx.x;
  if (i < n) cnt[i] = 1;  // self-loop contributes 1 to every node
}

__global__ __launch_bounds__(256) void k_hist(const int* __restrict__ dst, int e,
                                              int* __restrict__ cnt) {
  int i = blockIdx.x * 256 + threadIdx.x;
  if (i < e) atomicAdd(&cnt[dst[i]], 1);
}

__global__ __launch_bounds__(1024) void k_scan(const int* __restrict__ cnt,
                                               int* __restrict__ ptr,
                                               int* __restrict__ fill, int n) {
  __shared__ int lsum[1024];
  const int t = threadIdx.x;
  const int chunk = (n + 1023) >> 10;
  const int lo = t * chunk;
  const int hi = min(lo + chunk, n);
  int s = 0;
  for (int i = lo; i < hi; ++i) s += cnt[i];
  lsum[t] = s;
  __syncthreads();
  for (int off = 1; off < 1024; off <<= 1) {
    int v = (t >= off) ? lsum[t - off] : 0;
    __syncthreads();
    lsum[t] += v;
    __syncthreads();
  }
  if (t == 1023) ptr[n] = lsum[1023];
  int run = (t == 0) ? 0 : lsum[t - 1];
  for (int i = lo; i < hi; ++i) {
    ptr[i] = run;
    fill[i] = run;
    run += cnt[i];
  }
}

__global__ __launch_bounds__(256) void k_scatter(const int* __restrict__ srce,
                                                 const int* __restrict__ dste,
                                                 int e, int n,
                                                 int* __restrict__ fill,
                                                 int* __restrict__ srcs) {
  int i = blockIdx.x * 256 + threadIdx.x;
  if (i < e) {
    int pos = atomicAdd(&fill[dste[i]], 1);
    srcs[pos] = srce[i];
  } else if (i < e + n) {
    int v = i - e;  // self-loop
    int pos = atomicAdd(&fill[v], 1);
    srcs[pos] = v;
  }
}

// ---------------- f32 tiled GEMM: C[M,N2] = A[M,K] @ B[K,N2]; K%16==0, N2%64==0 ----------------
__global__ __launch_bounds__(256) void k_gemm(const float* __restrict__ A,
                                              const float* __restrict__ B,
                                              float* __restrict__ C,
                                              int M, int K, int N2) {
  __shared__ float As[16][68];
  __shared__ float Bs[16][68];
  const int bm = blockIdx.x * 64;
  const int bn = blockIdx.y * 64;
  const int t = threadIdx.x;
  const int tx = t & 15, ty = t >> 4;
  const int ar = t >> 2, ak = (t & 3) * 4;   // A tile: 64 rows x 16 k, float4 per thread
  const int kb = t >> 4, nb = (t & 15) * 4;  // B tile: 16 k x 64 cols, float4 per thread
  float acc[4][4] = {};
  for (int k0 = 0; k0 < K; k0 += 16) {
    float4 a4 = make_float4(0.f, 0.f, 0.f, 0.f);
    int arow = bm + ar;
    if (arow < M) a4 = *(const float4*)(A + (size_t)arow * K + k0 + ak);
    As[ak + 0][ar] = a4.x;
    As[ak + 1][ar] = a4.y;
    As[ak + 2][ar] = a4.z;
    As[ak + 3][ar] = a4.w;
    *(float4*)(&Bs[kb][nb]) = *(const float4*)(B + (size_t)(k0 + kb) * N2 + bn + nb);
    __syncthreads();
#pragma unroll
    for (int kk = 0; kk < 16; ++kk) {
      float a[4], b[4];
#pragma unroll
      for (int u = 0; u < 4; ++u) a[u] = As[kk][ty * 4 + u];
#pragma unroll
      for (int u = 0; u < 4; ++u) b[u] = Bs[kk][tx * 4 + u];
#pragma unroll
      for (int i2 = 0; i2 < 4; ++i2)
#pragma unroll
        for (int j2 = 0; j2 < 4; ++j2) acc[i2][j2] += a[i2] * b[j2];
    }
    __syncthreads();
  }
#pragma unroll
  for (int i2 = 0; i2 < 4; ++i2) {
    int row = bm + ty * 4 + i2;
    if (row < M) {
      float4 v = make_float4(acc[i2][0], acc[i2][1], acc[i2][2], acc[i2][3]);
      *(float4*)(C + (size_t)row * N2 + bn + tx * 4) = v;
    }
  }
}

// ---------------- per-node attention coefficients: als/ald[N,8] ----------------
__global__ __launch_bounds__(256) void k_attn(const float* __restrict__ h,
                                              const float* __restrict__ as_,
                                              const float* __restrict__ ad_,
                                              float* __restrict__ als,
                                              float* __restrict__ ald, int n) {
  int wid = (blockIdx.x * 256 + threadIdx.x) >> 6;
  int lane = threadIdx.x & 63;
  if (wid >= n) return;
  float4 hv = *(const float4*)(h + (size_t)wid * 256 + lane * 4);
  float4 av = *(const float4*)(as_ + lane * 4);
  float4 dv = *(const float4*)(ad_ + lane * 4);
  float ps = hv.x * av.x + hv.y * av.y + hv.z * av.z + hv.w * av.w;
  float pd = hv.x * dv.x + hv.y * dv.y + hv.z * dv.z + hv.w * dv.w;
  ps += __shfl_xor(ps, 1); pd += __shfl_xor(pd, 1);
  ps += __shfl_xor(ps, 2); pd += __shfl_xor(pd, 2);
  ps += __shfl_xor(ps, 4); pd += __shfl_xor(pd, 4);
  if ((lane & 7) == 0) {
    als[(size_t)wid * 8 + (lane >> 3)] = ps;
    ald[(size_t)wid * 8 + (lane >> 3)] = pd;
  }
}

// ---------------- GAT aggregation, one wave per destination node (H=8, C=32) ----------------
__global__ __launch_bounds__(256) void k_agg(const float* __restrict__ h,
                                             const float* __restrict__ als,
                                             const float* __restrict__ ald,
                                             const int* __restrict__ ptr,
                                             const int* __restrict__ srcs,
                                             const float* __restrict__ bias,
                                             float* __restrict__ out, int n) {
  int wid = (blockIdx.x * 256 + threadIdx.x) >> 6;
  int lane = threadIdx.x & 63;
  if (wid >= n) return;
  const int beg = ptr[wid], end = ptr[wid + 1];
  // phase 1: online softmax stats. lane = (edge slot 0..7) x (head 0..7)
  const int hslot = lane & 7;
  const int eslot = lane >> 3;
  const float aldh = ald[(size_t)wid * 8 + hslot];
  float m = -1e30f, s = 0.f;
  for (int j = beg + eslot; j < end; j += 8) {
    int sN = srcs[j];
    float lg = lr(als[(size_t)sN * 8 + hslot] + aldh, 0.2f);
    if (lg > m) {
      s = s * __expf(m - lg) + 1.f;
      m = lg;
    } else {
      s += __expf(lg - m);
    }
  }
#pragma unroll
  for (int off = 8; off < 64; off <<= 1) {
    float mo = __shfl_xor(m, off);
    float so = __shfl_xor(s, off);
    float M = fmaxf(m, mo);
    s = s * __expf(m - M) + so * __expf(mo - M);
    m = M;
  }
  // phase 2: lane handles channels 4*lane..4*lane+3 (head = lane>>3); fetch that head's stats
  const int hme = lane >> 3;
  const float mh = __shfl(m, hme);     // lane 'hme' holds stats for head hme
  const float sh = __shfl(s, hme);
  const float adh = __shfl(aldh, hme);
  const float inv = 1.f / (sh + 1e-16f);
  float4 acc = make_float4(0.f, 0.f, 0.f, 0.f);
  for (int j = beg; j < end; ++j) {
    int sN = srcs[j];
    float lg = lr(als[(size_t)sN * 8 + hme] + adh, 0.2f);
    float w = __expf(lg - mh);
    float4 hv = *(const float4*)(h + (size_t)sN * 256 + lane * 4);
    acc.x += w * hv.x;
    acc.y += w * hv.y;
    acc.z += w * hv.z;
    acc.w += w * hv.w;
  }
  float4 bv = *(const float4*)(bias + lane * 4);
  float4 o;
  o.x = acc.x * inv + bv.x;
  o.y = acc.y * inv + bv.y;
  o.z = acc.z * inv + bv.z;
  o.w = acc.w * inv + bv.w;
  *(float4*)(out + (size_t)wid * 256 + lane * 4) = o;
}

// ---------------- BatchNorm stats + fused apply/LeakyReLU(+residual) ----------------
__global__ __launch_bounds__(256) void k_bnstats(const float* __restrict__ x,
                                                 float* __restrict__ stats, int n) {
  int c = threadIdx.x;  // 256 channels
  float sum = 0.f, sq = 0.f;
  for (int r = blockIdx.x; r < n; r += gridDim.x) {
    float v = x[(size_t)r * 256 + c];
    sum += v;
    sq += v * v;
  }
  atomicAdd(&stats[c], sum);
  atomicAdd(&stats[256 + c], sq);
}

__global__ __launch_bounds__(256) void k_bnact(float* __restrict__ x,
                                               const float* __restrict__ stats,
                                               const float* __restrict__ g,
                                               const float* __restrict__ be,
                                               const float* __restrict__ res, int n) {
  const float invn = 1.f / (float)n;
  const int total = n * 256;
  for (int idx = blockIdx.x * 256 + threadIdx.x; idx < total; idx += gridDim.x * 256) {
    int c = idx & 255;
    float mu = stats[c] * invn;
    float var = stats[256 + c] * invn - mu * mu;
    float sc = g[c] * rsqrtf(var + 1e-5f);
    float v = (x[idx] - mu) * sc + be[c];
    v = v >= 0.f ? v : 0.01f * v;
    if (res) v += res[idx];
    x[idx] = v;
  }
}

// ---------------- layer 3: h3 = x @ W3 (256->4) + attention coefficients ----------------
__global__ __launch_bounds__(256) void k_gemm3(const float* __restrict__ x,
                                               const float* __restrict__ W3,
                                               const float* __restrict__ as3,
                                               const float* __restrict__ ad3,
                                               float* __restrict__ h3,
                                               float* __restrict__ als3,
                                               float* __restrict__ ald3, int n) {
  int wid = (blockIdx.x * 256 + threadIdx.x) >> 6;
  int lane = threadIdx.x & 63;
  if (wid >= n) return;
  float4 xv = *(const float4*)(x + (size_t)wid * 256 + lane * 4);
  const float4* Wp = (const float4*)W3 + lane * 4;  // rows 4*lane..4*lane+3 of W3[256,4]
  float4 w0 = Wp[0], w1 = Wp[1], w2 = Wp[2], w3 = Wp[3];
  float a0 = xv.x * w0.x + xv.y * w1.x + xv.z * w2.x + xv.w * w3.x;
  float a1 = xv.x * w0.y + xv.y * w1.y + xv.z * w2.y + xv.w * w3.y;
  float a2 = xv.x * w0.z + xv.y * w1.z + xv.z * w2.z + xv.w * w3.z;
  float a3 = xv.x * w0.w + xv.y * w1.w + xv.z * w2.w + xv.w * w3.w;
#pragma unroll
  for (int off = 1; off < 64; off <<= 1) {
    a0 += __shfl_xor(a0, off);
    a1 += __shfl_xor(a1, off);
    a2 += __shfl_xor(a2, off);
    a3 += __shfl_xor(a3, off);
  }
  if (lane == 0) {
    *(float4*)(h3 + (size_t)wid * 4) = make_float4(a0, a1, a2, a3);
    als3[wid] = a0 * as3[0] + a1 * as3[1] + a2 * as3[2] + a3 * as3[3];
    ald3[wid] = a0 * ad3[0] + a1 * ad3[1] + a2 * ad3[2] + a3 * ad3[3];
  }
}

// ---------------- layer 3 aggregation (1 head, 4 channels) -> d_out ----------------
__global__ __launch_bounds__(256) void k_agg3(const float* __restrict__ h3,
                                              const float* __restrict__ als3,
                                              const float* __restrict__ ald3,
                                              const int* __restrict__ ptr,
                                              const int* __restrict__ srcs,
                                              const float* __restrict__ b3,
                                              float* __restrict__ out, int n) {
  int wid = (blockIdx.x * 256 + threadIdx.x) >> 6;
  int lane = threadIdx.x & 63;
  if (wid >= n) return;
  const int beg = ptr[wid], end = ptr[wid + 1];
  const float aldh = ald3[wid];
  float m = -1e30f;
  for (int j = beg + lane; j < end; j += 64)
    m = fmaxf(m, lr(als3[srcs[j]] + aldh, 0.2f));
#pragma unroll
  for (int off = 1; off < 64; off <<= 1) m = fmaxf(m, __shfl_xor(m, off));
  float s = 0.f, a0 = 0.f, a1 = 0.f, a2 = 0.f, a3 = 0.f;
  for (int j = beg + lane; j < end; j += 64) {
    int sN = srcs[j];
    float wgt = __expf(lr(als3[sN] + aldh, 0.2f) - m);
    s += wgt;
    float4 hv = *(const float4*)(h3 + (size_t)sN * 4);
    a0 += wgt * hv.x;
    a1 += wgt * hv.y;
    a2 += wgt * hv.z;
    a3 += wgt * hv.w;
  }
#pragma unroll
  for (int off = 1; off < 64; off <<= 1) {
    s += __shfl_xor(s, off);
    a0 += __shfl_xor(a0, off);
    a1 += __shfl_xor(a1, off);
    a2 += __shfl_xor(a2, off);
    a3 += __shfl_xor(a3, off);
  }
  if (lane == 0) {
    float inv = 1.f / (s + 1e-16f);
    out[(size_t)wid * 4 + 0] = a0 * inv + b3[0];
    out[(size_t)wid * 4 + 1] = a1 * inv + b3[1];
    out[(size_t)wid * 4 + 2] = a2 * inv + b3[2];
    out[(size_t)wid * 4 + 3] = a3 * inv + b3[3];
  }
}

extern "C" void kernel_launch(void* const* d_in, const int* in_sizes, int n_in,
                              void* d_out, int out_size, void* d_ws, size_t ws_size,
                              hipStream_t stream) {
  const float* x   = (const float*)d_in[0];
  const int*   ei  = (const int*)d_in[1];
  const float* W1  = (const float*)d_in[2];
  const float* as1 = (const float*)d_in[3];
  const float* ad1 = (const float*)d_in[4];
  const float* b1  = (const float*)d_in[5];
  const float* g1  = (const float*)d_in[6];
  const float* be1 = (const float*)d_in[7];
  const float* W2  = (const float*)d_in[8];
  const float* as2 = (const float*)d_in[9];
  const float* ad2 = (const float*)d_in[10];
  const float* b2  = (const float*)d_in[11];
  const float* g2  = (const float*)d_in[12];
  const float* be2 = (const float*)d_in[13];
  const float* W3  = (const float*)d_in[14];
  const float* as3 = (const float*)d_in[15];
  const float* ad3 = (const float*)d_in[16];
  const float* b3  = (const float*)d_in[17];

  const int N = in_sizes[0] / 128;
  const int E = in_sizes[1] / 2;
  const int ET = E + N;
  float* out = (float*)d_out;

  char* w = (char*)d_ws;
  auto alloc = [&](size_t bytes) -> void* {
    void* p = (void*)w;
    w += (bytes + 255) & ~(size_t)255;
    return p;
  };
  int* ptr     = (int*)alloc((size_t)(N + 1) * 4);
  int* fill    = (int*)alloc((size_t)N * 4);
  int* cnt     = (int*)alloc((size_t)N * 4);
  int* srcs    = (int*)alloc((size_t)ET * 4);
  float* hbuf  = (float*)alloc((size_t)N * 256 * 4);
  float* agg1  = (float*)alloc((size_t)N * 256 * 4);
  float* agg2  = (float*)alloc((size_t)N * 256 * 4);
  float* als   = (float*)alloc((size_t)N * 8 * 4);
  float* ald   = (float*)alloc((size_t)N * 8 * 4);
  float* h3    = (float*)alloc((size_t)N * 4 * 4);
  float* als3  = (float*)alloc((size_t)N * 4);
  float* ald3  = (float*)alloc((size_t)N * 4);
  float* stat1 = (float*)alloc(512 * 4);
  float* stat2 = (float*)alloc(512 * 4);

  const int* esrc = ei;
  const int* edst = ei + E;

  hipMemsetAsync(stat1, 0, 512 * 4, stream);
  hipMemsetAsync(stat2, 0, 512 * 4, stream);

  // CSR (shared by all three layers)
  k_init_cnt<<<(N + 255) / 256, 256, 0, stream>>>(cnt, N);
  k_hist<<<(E + 255) / 256, 256, 0, stream>>>(edst, E, cnt);
  k_scan<<<1, 1024, 0, stream>>>(cnt, ptr, fill, N);
  k_scatter<<<(ET + 255) / 256, 256, 0, stream>>>(esrc, edst, E, N, fill, srcs);

  const dim3 gemm_grid((N + 63) / 64, 4);
  const int wblocks = (N + 3) / 4;  // 4 waves per 256-thread block

  // layer 1
  k_gemm<<<gemm_grid, 256, 0, stream>>>(x, W1, hbuf, N, 128, 256);
  k_attn<<<wblocks, 256, 0, stream>>>(hbuf, as1, ad1, als, ald, N);
  k_agg<<<wblocks, 256, 0, stream>>>(hbuf, als, ald, ptr, srcs, b1, agg1, N);
  k_bnstats<<<512, 256, 0, stream>>>(agg1, stat1, N);
  k_bnact<<<2048, 256, 0, stream>>>(agg1, stat1, g1, be1, nullptr, N);

  // layer 2 (+ residual)
  k_gemm<<<gemm_grid, 256, 0, stream>>>(agg1, W2, hbuf, N, 256, 256);
  k_attn<<<wblocks, 256, 0, stream>>>(hbuf, as2, ad2, als, ald, N);
  k_agg<<<wblocks, 256, 0, stream>>>(hbuf, als, ald, ptr, srcs, b2, agg2, N);
  k_bnstats<<<512, 256, 0, stream>>>(agg2, stat2, N);
  k_bnact<<<2048, 256, 0, stream>>>(agg2, stat2, g2, be2, agg1, N);

  // layer 3 -> output
  k_gemm3<<<wblocks, 256, 0, stream>>>(agg2, W3, as3, ad3, h3, als3, ald3, N);
  k_agg3<<<wblocks, 256, 0, stream>>>(h3, als3, ald3, ptr, srcs, b3, out, N);
}

// Round 2
// 636.504 us; speedup vs baseline: 1.2607x; 1.2607x over previous
//
#include <hip/hip_runtime.h>

typedef __attribute__((ext_vector_type(8))) short bf16x8;
typedef __attribute__((ext_vector_type(4))) float f32x4;

__device__ __forceinline__ float lrelu(float x, float s) { return x >= 0.f ? x : s * x; }
__device__ __forceinline__ float b2f(unsigned short u) {
  union { unsigned int i; float f; } v; v.i = ((unsigned int)u) << 16; return v.f;
}
__device__ __forceinline__ unsigned short f2b(float f) {
  union { float f; unsigned int i; } v; v.f = f;
  unsigned int r = v.i + 0x7fffu + ((v.i >> 16) & 1u);
  return (unsigned short)(r >> 16);
}

// ---------------- CSR build (by destination), reused for all 3 layers ----------------
__global__ __launch_bounds__(256) void k_init_cnt(int* __restrict__ cnt, int n) {
  int i = blockIdx.x * 256 + threadIdx.x;
  if (i < n) cnt[i] = 1;  // self-loop
}

__global__ __launch_bounds__(256) void k_hist(const int* __restrict__ dst, int e,
                                              int* __restrict__ cnt) {
  int i = blockIdx.x * 256 + threadIdx.x;
  if (i < e) atomicAdd(&cnt[dst[i]], 1);
}

__global__ __launch_bounds__(1024) void k_scan(const int* __restrict__ cnt,
                                               int* __restrict__ ptr,
                                               int* __restrict__ fill, int n) {
  __shared__ int lsum[1024];
  const int t = threadIdx.x;
  const int chunk = (n + 1023) >> 10;
  const int lo = t * chunk;
  const int hi = min(lo + chunk, n);
  int s = 0;
  for (int i = lo; i < hi; ++i) s += cnt[i];
  lsum[t] = s;
  __syncthreads();
  for (int off = 1; off < 1024; off <<= 1) {
    int v = (t >= off) ? lsum[t - off] : 0;
    __syncthreads();
    lsum[t] += v;
    __syncthreads();
  }
  if (t == 1023) ptr[n] = lsum[1023];
  int run = (t == 0) ? 0 : lsum[t - 1];
  for (int i = lo; i < hi; ++i) {
    ptr[i] = run;
    fill[i] = run;
    run += cnt[i];
  }
}

__global__ __launch_bounds__(256) void k_scatter(const int* __restrict__ srce,
                                                 const int* __restrict__ dste,
                                                 int e, int n,
                                                 int* __restrict__ fill,
                                                 int* __restrict__ srcs) {
  int i = blockIdx.x * 256 + threadIdx.x;
  if (i < e) {
    int pos = atomicAdd(&fill[dste[i]], 1);
    srcs[pos] = srce[i];
  } else if (i < e + n) {
    int v = i - e;
    int pos = atomicAdd(&fill[v], 1);
    srcs[pos] = v;
  }
}

// ---------------- dtype conversions ----------------
__global__ __launch_bounds__(256) void k_f2b(const float* __restrict__ in,
                                             unsigned short* __restrict__ out, int n4) {
  int i = blockIdx.x * 256 + threadIdx.x;
  if (i < n4) {
    float4 v = ((const float4*)in)[i];
    ushort4 o;
    o.x = f2b(v.x); o.y = f2b(v.y); o.z = f2b(v.z); o.w = f2b(v.w);
    ((ushort4*)out)[i] = o;
  }
}

// W[K][Nn] f32 -> WT[Nn][K] bf16
__global__ __launch_bounds__(256) void k_cvtT(const float* __restrict__ W,
                                              unsigned short* __restrict__ WT,
                                              int K, int Nn) {
  int i = blockIdx.x * 256 + threadIdx.x;
  if (i < K * Nn) {
    int n = i / K, k = i - n * K;
    WT[i] = f2b(W[(size_t)k * Nn + n]);
  }
}

// ---------------- bf16 MFMA GEMM: C[M,Nn] = A[M,K] @ BT[Nn,K]^T ----------------
// 128x128 tile, 4 waves (2x2), each wave 64x64 via 4x4 frags of 16x16x32.
__global__ __launch_bounds__(256) void k_mfma(const unsigned short* __restrict__ A,
                                              const unsigned short* __restrict__ BT,
                                              unsigned short* __restrict__ C,
                                              int M, int Nn, int K) {
  __shared__ unsigned int Asu[128 * 20];  // rows of 32 bf16 + pad to 40 (80B)
  __shared__ unsigned int Bsu[128 * 20];
  const int tid = threadIdx.x;
  const int bm = blockIdx.x * 128, bn = blockIdx.y * 128;
  const int w = tid >> 6, lane = tid & 63;
  const int wm = w >> 1, wn = w & 1;
  const int l16 = lane & 15, lg = lane >> 4;
  f32x4 acc[4][4] = {};
  for (int k0 = 0; k0 < K; k0 += 32) {
#pragma unroll
    for (int rep = 0; rep < 2; ++rep) {
      int ci = tid + rep * 256;       // 0..511
      int row = ci >> 2, cg = ci & 3; // 128 rows x 4 chunks of 8 bf16
      int ar = bm + row;
      ar = ar < M ? ar : M - 1;
      uint4 av = *(const uint4*)(A + (size_t)ar * K + k0 + cg * 8);
      *(uint4*)&Asu[row * 20 + cg * 4] = av;
      uint4 bv = *(const uint4*)(BT + (size_t)(bn + row) * K + k0 + cg * 8);
      *(uint4*)&Bsu[row * 20 + cg * 4] = bv;
    }
    __syncthreads();
    bf16x8 aF[4], bF[4];
#pragma unroll
    for (int mi = 0; mi < 4; ++mi)
      aF[mi] = *(const bf16x8*)&Asu[(wm * 64 + mi * 16 + l16) * 20 + lg * 4];
#pragma unroll
    for (int ni = 0; ni < 4; ++ni)
      bF[ni] = *(const bf16x8*)&Bsu[(wn * 64 + ni * 16 + l16) * 20 + lg * 4];
#pragma unroll
    for (int mi = 0; mi < 4; ++mi)
#pragma unroll
      for (int ni = 0; ni < 4; ++ni)
        acc[mi][ni] =
            __builtin_amdgcn_mfma_f32_16x16x32_bf16(aF[mi], bF[ni], acc[mi][ni], 0, 0, 0);
    __syncthreads();
  }
  // epilogue: C/D layout col=lane&15, row=(lane>>4)*4+reg
#pragma unroll
  for (int mi = 0; mi < 4; ++mi) {
#pragma unroll
    for (int r = 0; r < 4; ++r) {
      int grow = bm + wm * 64 + mi * 16 + lg * 4 + r;
      if (grow < M) {
#pragma unroll
        for (int ni = 0; ni < 4; ++ni) {
          int gcol = bn + wn * 64 + ni * 16 + l16;
          C[(size_t)grow * Nn + gcol] = f2b(acc[mi][ni][r]);
        }
      }
    }
  }
}

// ---------------- per-node attention coefficients from bf16 h ----------------
__global__ __launch_bounds__(256) void k_attn(const unsigned short* __restrict__ h,
                                              const float* __restrict__ as_,
                                              const float* __restrict__ ad_,
                                              float* __restrict__ als,
                                              float* __restrict__ ald, int n) {
  int wid = (blockIdx.x * 256 + threadIdx.x) >> 6;
  int lane = threadIdx.x & 63;
  if (wid >= n) return;
  ushort4 hv = *(const ushort4*)(h + (size_t)wid * 256 + lane * 4);
  float hx = b2f(hv.x), hy = b2f(hv.y), hz = b2f(hv.z), hw = b2f(hv.w);
  float4 av = *(const float4*)(as_ + lane * 4);
  float4 dv = *(const float4*)(ad_ + lane * 4);
  float ps = hx * av.x + hy * av.y + hz * av.z + hw * av.w;
  float pd = hx * dv.x + hy * dv.y + hz * dv.z + hw * dv.w;
  ps += __shfl_xor(ps, 1); pd += __shfl_xor(pd, 1);
  ps += __shfl_xor(ps, 2); pd += __shfl_xor(pd, 2);
  ps += __shfl_xor(ps, 4); pd += __shfl_xor(pd, 4);
  if ((lane & 7) == 0) {
    als[(size_t)wid * 8 + (lane >> 3)] = ps;
    ald[(size_t)wid * 8 + (lane >> 3)] = pd;
  }
}

// ---------------- single-pass online-softmax GAT aggregation (bf16 gather) ----------------
__global__ __launch_bounds__(256) void k_agg(const unsigned short* __restrict__ h,
                                             const float* __restrict__ als,
                                             const float* __restrict__ ald,
                                             const int* __restrict__ ptr,
                                             const int* __restrict__ srcs,
                                             const float* __restrict__ bias,
                                             float* __restrict__ out, int n) {
  int wid = (blockIdx.x * 256 + threadIdx.x) >> 6;
  int lane = threadIdx.x & 63;
  if (wid >= n) return;
  const int beg = ptr[wid], end = ptr[wid + 1];
  const int hme = lane >> 3;  // head of my 4 channels (channels 4*lane..4*lane+3)
  const float adh = ald[(size_t)wid * 8 + hme];
  float m = -1e30f, s = 0.f;
  float ax = 0.f, ay = 0.f, az = 0.f, aw = 0.f;
  for (int j = beg; j < end; ++j) {
    int sN = srcs[j];
    float lg = lrelu(als[(size_t)sN * 8 + hme] + adh, 0.2f);
    float mn = fmaxf(m, lg);
    float c = __expf(m - mn);
    float wt = __expf(lg - mn);
    m = mn;
    s = s * c + wt;
    ushort4 hv = *(const ushort4*)(h + (size_t)sN * 256 + lane * 4);
    ax = ax * c + wt * b2f(hv.x);
    ay = ay * c + wt * b2f(hv.y);
    az = az * c + wt * b2f(hv.z);
    aw = aw * c + wt * b2f(hv.w);
  }
  const float inv = 1.f / (s + 1e-16f);
  float4 bv = *(const float4*)(bias + lane * 4);
  float4 o;
  o.x = ax * inv + bv.x;
  o.y = ay * inv + bv.y;
  o.z = az * inv + bv.z;
  o.w = aw * inv + bv.w;
  *(float4*)(out + (size_t)wid * 256 + lane * 4) = o;
}

// ---------------- BatchNorm stats + fused apply/LeakyReLU(+residual) ----------------
__global__ __launch_bounds__(256) void k_bnstats(const float* __restrict__ x,
                                                 float* __restrict__ stats, int n) {
  int c = threadIdx.x;
  float sum = 0.f, sq = 0.f;
  for (int r = blockIdx.x; r < n; r += gridDim.x) {
    float v = x[(size_t)r * 256 + c];
    sum += v;
    sq += v * v;
  }
  atomicAdd(&stats[c], sum);
  atomicAdd(&stats[256 + c], sq);
}

__global__ __launch_bounds__(256) void k_bnact(float* __restrict__ x,
                                               const float* __restrict__ stats,
                                               const float* __restrict__ ga,
                                               const float* __restrict__ be,
                                               const float* __restrict__ res,
                                               unsigned short* __restrict__ xb,
                                               int writef32, int n) {
  const float invn = 1.f / (float)n;
  const int tot4 = n * 64;
  for (int t = blockIdx.x * 256 + threadIdx.x; t < tot4; t += gridDim.x * 256) {
    int i0 = t * 4;
    int c = i0 & 255;
    float4 xv = *(const float4*)(x + i0);
    float4 sm = *(const float4*)(stats + c);
    float4 sq = *(const float4*)(stats + 256 + c);
    float4 gv = *(const float4*)(ga + c);
    float4 bev = *(const float4*)(be + c);
    float o0, o1, o2, o3, mu, var, sc;
    mu = sm.x * invn; var = sq.x * invn - mu * mu; sc = gv.x * rsqrtf(var + 1e-5f);
    o0 = (xv.x - mu) * sc + bev.x; o0 = o0 >= 0.f ? o0 : 0.01f * o0;
    mu = sm.y * invn; var = sq.y * invn - mu * mu; sc = gv.y * rsqrtf(var + 1e-5f);
    o1 = (xv.y - mu) * sc + bev.y; o1 = o1 >= 0.f ? o1 : 0.01f * o1;
    mu = sm.z * invn; var = sq.z * invn - mu * mu; sc = gv.z * rsqrtf(var + 1e-5f);
    o2 = (xv.z - mu) * sc + bev.z; o2 = o2 >= 0.f ? o2 : 0.01f * o2;
    mu = sm.w * invn; var = sq.w * invn - mu * mu; sc = gv.w * rsqrtf(var + 1e-5f);
    o3 = (xv.w - mu) * sc + bev.w; o3 = o3 >= 0.f ? o3 : 0.01f * o3;
    if (res) {
      float4 rv = *(const float4*)(res + i0);
      o0 += rv.x; o1 += rv.y; o2 += rv.z; o3 += rv.w;
    }
    if (writef32) *(float4*)(x + i0) = make_float4(o0, o1, o2, o3);
    ushort4 ob;
    ob.x = f2b(o0); ob.y = f2b(o1); ob.z = f2b(o2); ob.w = f2b(o3);
    *(ushort4*)(xb + i0) = ob;
  }
}

// ---------------- layer 3: h3 = x @ W3 (256->4) + attention coefficients ----------------
__global__ __launch_bounds__(256) void k_gemm3(const unsigned short* __restrict__ x,
                                               const float* __restrict__ W3,
                                               const float* __restrict__ as3,
                                               const float* __restrict__ ad3,
                                               float* __restrict__ h3,
                                               float* __restrict__ als3,
                                               float* __restrict__ ald3, int n) {
  int wid = (blockIdx.x * 256 + threadIdx.x) >> 6;
  int lane = threadIdx.x & 63;
  if (wid >= n) return;
  ushort4 xu = *(const ushort4*)(x + (size_t)wid * 256 + lane * 4);
  float x0 = b2f(xu.x), x1 = b2f(xu.y), x2 = b2f(xu.z), x3 = b2f(xu.w);
  const float4* Wp = (const float4*)W3 + lane * 4;  // rows 4*lane.. of W3[256,4]
  float4 w0 = Wp[0], w1 = Wp[1], w2 = Wp[2], w3 = Wp[3];
  float a0 = x0 * w0.x + x1 * w1.x + x2 * w2.x + x3 * w3.x;
  float a1 = x0 * w0.y + x1 * w1.y + x2 * w2.y + x3 * w3.y;
  float a2 = x0 * w0.z + x1 * w1.z + x2 * w2.z + x3 * w3.z;
  float a3 = x0 * w0.w + x1 * w1.w + x2 * w2.w + x3 * w3.w;
#pragma unroll
  for (int off = 1; off < 64; off <<= 1) {
    a0 += __shfl_xor(a0, off);
    a1 += __shfl_xor(a1, off);
    a2 += __shfl_xor(a2, off);
    a3 += __shfl_xor(a3, off);
  }
  if (lane == 0) {
    *(float4*)(h3 + (size_t)wid * 4) = make_float4(a0, a1, a2, a3);
    als3[wid] = a0 * as3[0] + a1 * as3[1] + a2 * as3[2] + a3 * as3[3];
    ald3[wid] = a0 * ad3[0] + a1 * ad3[1] + a2 * ad3[2] + a3 * ad3[3];
  }
}

// ---------------- layer 3 aggregation (1 head, 4 channels) -> d_out ----------------
__global__ __launch_bounds__(256) void k_agg3(const float* __restrict__ h3,
                                              const float* __restrict__ als3,
                                              const float* __restrict__ ald3,
                                              const int* __restrict__ ptr,
                                              const int* __restrict__ srcs,
                                              const float* __restrict__ b3,
                                              float* __restrict__ out, int n) {
  int wid = (blockIdx.x * 256 + threadIdx.x) >> 6;
  int lane = threadIdx.x & 63;
  if (wid >= n) return;
  const int beg = ptr[wid], end = ptr[wid + 1];
  const float aldh = ald3[wid];
  float m = -1e30f;
  for (int j = beg + lane; j < end; j += 64)
    m = fmaxf(m, lrelu(als3[srcs[j]] + aldh, 0.2f));
#pragma unroll
  for (int off = 1; off < 64; off <<= 1) m = fmaxf(m, __shfl_xor(m, off));
  float s = 0.f, a0 = 0.f, a1 = 0.f, a2 = 0.f, a3 = 0.f;
  for (int j = beg + lane; j < end; j += 64) {
    int sN = srcs[j];
    float wgt = __expf(lrelu(als3[sN] + aldh, 0.2f) - m);
    s += wgt;
    float4 hv = *(const float4*)(h3 + (size_t)sN * 4);
    a0 += wgt * hv.x;
    a1 += wgt * hv.y;
    a2 += wgt * hv.z;
    a3 += wgt * hv.w;
  }
#pragma unroll
  for (int off = 1; off < 64; off <<= 1) {
    s += __shfl_xor(s, off);
    a0 += __shfl_xor(a0, off);
    a1 += __shfl_xor(a1, off);
    a2 += __shfl_xor(a2, off);
    a3 += __shfl_xor(a3, off);
  }
  if (lane == 0) {
    float inv = 1.f / (s + 1e-16f);
    out[(size_t)wid * 4 + 0] = a0 * inv + b3[0];
    out[(size_t)wid * 4 + 1] = a1 * inv + b3[1];
    out[(size_t)wid * 4 + 2] = a2 * inv + b3[2];
    out[(size_t)wid * 4 + 3] = a3 * inv + b3[3];
  }
}

extern "C" void kernel_launch(void* const* d_in, const int* in_sizes, int n_in,
                              void* d_out, int out_size, void* d_ws, size_t ws_size,
                              hipStream_t stream) {
  const float* x   = (const float*)d_in[0];
  const int*   ei  = (const int*)d_in[1];
  const float* W1  = (const float*)d_in[2];
  const float* as1 = (const float*)d_in[3];
  const float* ad1 = (const float*)d_in[4];
  const float* b1  = (const float*)d_in[5];
  const float* ga1 = (const float*)d_in[6];
  const float* be1 = (const float*)d_in[7];
  const float* W2  = (const float*)d_in[8];
  const float* as2 = (const float*)d_in[9];
  const float* ad2 = (const float*)d_in[10];
  const float* b2  = (const float*)d_in[11];
  const float* ga2 = (const float*)d_in[12];
  const float* be2 = (const float*)d_in[13];
  const float* W3  = (const float*)d_in[14];
  const float* as3 = (const float*)d_in[15];
  const float* ad3 = (const float*)d_in[16];
  const float* b3  = (const float*)d_in[17];

  const int N = in_sizes[0] / 128;
  const int E = in_sizes[1] / 2;
  const int ET = E + N;
  float* out = (float*)d_out;

  char* w = (char*)d_ws;
  auto alloc = [&](size_t bytes) -> void* {
    void* p = (void*)w;
    w += (bytes + 255) & ~(size_t)255;
    return p;
  };
  int* ptr              = (int*)alloc((size_t)(N + 1) * 4);
  int* fill             = (int*)alloc((size_t)N * 4);
  int* cnt              = (int*)alloc((size_t)N * 4);
  int* srcs             = (int*)alloc((size_t)ET * 4);
  unsigned short* hbuf  = (unsigned short*)alloc((size_t)N * 256 * 2);
  float* agg1           = (float*)alloc((size_t)N * 256 * 4);
  unsigned short* a2b   = (unsigned short*)alloc((size_t)N * 256 * 2);
  float* als            = (float*)alloc((size_t)N * 8 * 4);
  float* ald            = (float*)alloc((size_t)N * 8 * 4);
  float* h3             = (float*)alloc((size_t)N * 4 * 4);
  float* als3           = (float*)alloc((size_t)N * 4);
  float* ald3           = (float*)alloc((size_t)N * 4);
  float* stats          = (float*)alloc(1024 * 4);  // [stat1 | stat2]
  // union region: early {xb, w1t, w2t, a1b}, later agg2 (f32, full region)
  char* uni             = (char*)alloc((size_t)N * 256 * 4);
  unsigned short* xb    = (unsigned short*)uni;                       // N*128 bf16
  unsigned short* w1t   = (unsigned short*)(uni + (size_t)N * 128 * 2);  // 256x128
  unsigned short* w2t   = w1t + 256 * 128;                            // 256x256
  unsigned short* a1b   = w2t + 256 * 256;                            // N*256 bf16
  float* agg2           = (float*)uni;  // valid after gemm2 consumed xb/a1b/w2t

  const int* esrc = ei;
  const int* edst = ei + E;

  hipMemsetAsync(stats, 0, 1024 * 4, stream);

  // CSR (shared by all three layers)
  k_init_cnt<<<(N + 255) / 256, 256, 0, stream>>>(cnt, N);
  k_hist<<<(E + 255) / 256, 256, 0, stream>>>(edst, E, cnt);
  k_scan<<<1, 1024, 0, stream>>>(cnt, ptr, fill, N);
  k_scatter<<<(ET + 255) / 256, 256, 0, stream>>>(esrc, edst, E, N, fill, srcs);

  // bf16 conversions
  k_f2b<<<((N * 32) + 255) / 256, 256, 0, stream>>>(x, xb, N * 32);
  k_cvtT<<<(256 * 128 + 255) / 256, 256, 0, stream>>>(W1, w1t, 128, 256);
  k_cvtT<<<(256 * 256 + 255) / 256, 256, 0, stream>>>(W2, w2t, 256, 256);

  const dim3 gemm_grid((N + 127) / 128, 2);
  const int wblocks = (N + 3) / 4;  // 4 waves per 256-thread block

  // layer 1
  k_mfma<<<gemm_grid, 256, 0, stream>>>(xb, w1t, hbuf, N, 256, 128);
  k_attn<<<wblocks, 256, 0, stream>>>(hbuf, as1, ad1, als, ald, N);
  k_agg<<<wblocks, 256, 0, stream>>>(hbuf, als, ald, ptr, srcs, b1, agg1, N);
  k_bnstats<<<512, 256, 0, stream>>>(agg1, stats, N);
  k_bnact<<<2048, 256, 0, stream>>>(agg1, stats, ga1, be1, nullptr, a1b, 1, N);

  // layer 2 (+ residual)
  k_mfma<<<gemm_grid, 256, 0, stream>>>(a1b, w2t, hbuf, N, 256, 256);
  k_attn<<<wblocks, 256, 0, stream>>>(hbuf, as2, ad2, als, ald, N);
  k_agg<<<wblocks, 256, 0, stream>>>(hbuf, als, ald, ptr, srcs, b2, agg2, N);
  k_bnstats<<<512, 256, 0, stream>>>(agg2, stats + 512, N);
  k_bnact<<<2048, 256, 0, stream>>>(agg2, stats + 512, ga2, be2, agg1, a2b, 0, N);

  // layer 3 -> output
  k_gemm3<<<wblocks, 256, 0, stream>>>(a2b, W3, as3, ad3, h3, als3, ald3, N);
  k_agg3<<<wblocks, 256, 0, stream>>>(h3, als3, ald3, ptr, srcs, b3, out, N);
}

// Round 3
// 541.323 us; speedup vs baseline: 1.4824x; 1.1758x over previous
//
#include <hip/hip_runtime.h>

typedef __attribute__((ext_vector_type(8))) short bf16x8;
typedef __attribute__((ext_vector_type(4))) float f32x4;

__device__ __forceinline__ float lrelu(float x, float s) { return x >= 0.f ? x : s * x; }
__device__ __forceinline__ float b2f(unsigned short u) {
  union { unsigned int i; float f; } v; v.i = ((unsigned int)u) << 16; return v.f;
}
__device__ __forceinline__ unsigned short f2b(float f) {
  union { float f; unsigned int i; } v; v.f = f;
  unsigned int r = v.i + 0x7fffu + ((v.i >> 16) & 1u);
  return (unsigned short)(r >> 16);
}

// ---------------- CSR build (by destination), reused for all 3 layers ----------------
__global__ __launch_bounds__(256) void k_init_cnt(int* __restrict__ cnt, int n) {
  int i = blockIdx.x * 256 + threadIdx.x;
  if (i < n) cnt[i] = 1;  // self-loop
}

__global__ __launch_bounds__(256) void k_hist(const int* __restrict__ dst, int e,
                                              int* __restrict__ cnt) {
  int i = blockIdx.x * 256 + threadIdx.x;
  if (i < e) atomicAdd(&cnt[dst[i]], 1);
}

// ---- 3-phase parallel exclusive scan of cnt[0..n) -> ptr/fill, ptr[n]=total ----
// phase 1: per-block (1024 elems) sums
__global__ __launch_bounds__(256) void k_bsum(const int* __restrict__ cnt,
                                              int* __restrict__ bsum, int n) {
  const int base = blockIdx.x * 1024;
  const int t = threadIdx.x;
  int s = 0;
#pragma unroll
  for (int i = 0; i < 4; ++i) {
    int idx = base + t + i * 256;
    if (idx < n) s += cnt[idx];
  }
#pragma unroll
  for (int off = 1; off < 64; off <<= 1) s += __shfl_xor(s, off);
  __shared__ int ws[4];
  const int lane = t & 63, w = t >> 6;
  if (lane == 0) ws[w] = s;
  __syncthreads();
  if (t == 0) bsum[blockIdx.x] = ws[0] + ws[1] + ws[2] + ws[3];
}

// phase 2: one wave scans the block sums (B <= 64)
__global__ __launch_bounds__(64) void k_scanb(const int* __restrict__ bsum,
                                              int* __restrict__ boff,
                                              int* __restrict__ ptrN, int B) {
  const int lane = threadIdx.x;
  int v = lane < B ? bsum[lane] : 0;
  int incl = v;
#pragma unroll
  for (int off = 1; off < 64; off <<= 1) {
    int u = __shfl_up(incl, off);
    if (lane >= off) incl += u;
  }
  if (lane < B) boff[lane] = incl - v;
  if (lane == 63) *ptrN = incl;
}

// phase 3: per-block local scan + global offset
__global__ __launch_bounds__(256) void k_scanl(const int* __restrict__ cnt,
                                               const int* __restrict__ boff,
                                               int* __restrict__ ptr,
                                               int* __restrict__ fill, int n) {
  __shared__ int ws[4];
  const int t = threadIdx.x;
  const int base = blockIdx.x * 1024 + t * 4;
  int v0 = base + 0 < n ? cnt[base + 0] : 0;
  int v1 = base + 1 < n ? cnt[base + 1] : 0;
  int v2 = base + 2 < n ? cnt[base + 2] : 0;
  int v3 = base + 3 < n ? cnt[base + 3] : 0;
  const int tsum = v0 + v1 + v2 + v3;
  const int lane = t & 63, w = t >> 6;
  int incl = tsum;
#pragma unroll
  for (int off = 1; off < 64; off <<= 1) {
    int u = __shfl_up(incl, off);
    if (lane >= off) incl += u;
  }
  if (lane == 63) ws[w] = incl;
  __syncthreads();
  int excl = boff[blockIdx.x] + incl - tsum;
  for (int i = 0; i < w; ++i) excl += ws[i];
  if (base + 0 < n) { ptr[base + 0] = excl; fill[base + 0] = excl; }
  excl += v0;
  if (base + 1 < n) { ptr[base + 1] = excl; fill[base + 1] = excl; }
  excl += v1;
  if (base + 2 < n) { ptr[base + 2] = excl; fill[base + 2] = excl; }
  excl += v2;
  if (base + 3 < n) { ptr[base + 3] = excl; fill[base + 3] = excl; }
}

__global__ __launch_bounds__(256) void k_scatter(const int* __restrict__ srce,
                                                 const int* __restrict__ dste,
                                                 int e, int n,
                                                 int* __restrict__ fill,
                                                 int* __restrict__ srcs) {
  int i = blockIdx.x * 256 + threadIdx.x;
  if (i < e) {
    int pos = atomicAdd(&fill[dste[i]], 1);
    srcs[pos] = srce[i];
  } else if (i < e + n) {
    int v = i - e;
    int pos = atomicAdd(&fill[v], 1);
    srcs[pos] = v;
  }
}

// ---------------- dtype conversions ----------------
__global__ __launch_bounds__(256) void k_f2b(const float* __restrict__ in,
                                             unsigned short* __restrict__ out, int n4) {
  int i = blockIdx.x * 256 + threadIdx.x;
  if (i < n4) {
    float4 v = ((const float4*)in)[i];
    ushort4 o;
    o.x = f2b(v.x); o.y = f2b(v.y); o.z = f2b(v.z); o.w = f2b(v.w);
    ((ushort4*)out)[i] = o;
  }
}

// W[K][Nn] f32 -> WT[Nn][K] bf16
__global__ __launch_bounds__(256) void k_cvtT(const float* __restrict__ W,
                                              unsigned short* __restrict__ WT,
                                              int K, int Nn) {
  int i = blockIdx.x * 256 + threadIdx.x;
  if (i < K * Nn) {
    int n = i / K, k = i - n * K;
    WT[i] = f2b(W[(size_t)k * Nn + n]);
  }
}

// ---------------- bf16 MFMA GEMM: C[M,Nn] = A[M,K] @ BT[Nn,K]^T ----------------
__global__ __launch_bounds__(256) void k_mfma(const unsigned short* __restrict__ A,
                                              const unsigned short* __restrict__ BT,
                                              unsigned short* __restrict__ C,
                                              int M, int Nn, int K) {
  __shared__ unsigned int Asu[128 * 20];  // rows of 32 bf16 + pad to 40 (80B)
  __shared__ unsigned int Bsu[128 * 20];
  const int tid = threadIdx.x;
  const int bm = blockIdx.x * 128, bn = blockIdx.y * 128;
  const int w = tid >> 6, lane = tid & 63;
  const int wm = w >> 1, wn = w & 1;
  const int l16 = lane & 15, lg = lane >> 4;
  f32x4 acc[4][4] = {};
  for (int k0 = 0; k0 < K; k0 += 32) {
#pragma unroll
    for (int rep = 0; rep < 2; ++rep) {
      int ci = tid + rep * 256;       // 0..511
      int row = ci >> 2, cg = ci & 3; // 128 rows x 4 chunks of 8 bf16
      int ar = bm + row;
      ar = ar < M ? ar : M - 1;
      uint4 av = *(const uint4*)(A + (size_t)ar * K + k0 + cg * 8);
      *(uint4*)&Asu[row * 20 + cg * 4] = av;
      uint4 bv = *(const uint4*)(BT + (size_t)(bn + row) * K + k0 + cg * 8);
      *(uint4*)&Bsu[row * 20 + cg * 4] = bv;
    }
    __syncthreads();
    bf16x8 aF[4], bF[4];
#pragma unroll
    for (int mi = 0; mi < 4; ++mi)
      aF[mi] = *(const bf16x8*)&Asu[(wm * 64 + mi * 16 + l16) * 20 + lg * 4];
#pragma unroll
    for (int ni = 0; ni < 4; ++ni)
      bF[ni] = *(const bf16x8*)&Bsu[(wn * 64 + ni * 16 + l16) * 20 + lg * 4];
#pragma unroll
    for (int mi = 0; mi < 4; ++mi)
#pragma unroll
      for (int ni = 0; ni < 4; ++ni)
        acc[mi][ni] =
            __builtin_amdgcn_mfma_f32_16x16x32_bf16(aF[mi], bF[ni], acc[mi][ni], 0, 0, 0);
    __syncthreads();
  }
#pragma unroll
  for (int mi = 0; mi < 4; ++mi) {
#pragma unroll
    for (int r = 0; r < 4; ++r) {
      int grow = bm + wm * 64 + mi * 16 + lg * 4 + r;
      if (grow < M) {
#pragma unroll
        for (int ni = 0; ni < 4; ++ni) {
          int gcol = bn + wn * 64 + ni * 16 + l16;
          C[(size_t)grow * Nn + gcol] = f2b(acc[mi][ni][r]);
        }
      }
    }
  }
}

// ---------------- per-node attention coefficients from bf16 h ----------------
__global__ __launch_bounds__(256) void k_attn(const unsigned short* __restrict__ h,
                                              const float* __restrict__ as_,
                                              const float* __restrict__ ad_,
                                              float* __restrict__ als,
                                              float* __restrict__ ald, int n) {
  int wid = (blockIdx.x * 256 + threadIdx.x) >> 6;
  int lane = threadIdx.x & 63;
  if (wid >= n) return;
  ushort4 hv = *(const ushort4*)(h + (size_t)wid * 256 + lane * 4);
  float hx = b2f(hv.x), hy = b2f(hv.y), hz = b2f(hv.z), hw = b2f(hv.w);
  float4 av = *(const float4*)(as_ + lane * 4);
  float4 dv = *(const float4*)(ad_ + lane * 4);
  float ps = hx * av.x + hy * av.y + hz * av.z + hw * av.w;
  float pd = hx * dv.x + hy * dv.y + hz * dv.z + hw * dv.w;
  ps += __shfl_xor(ps, 1); pd += __shfl_xor(pd, 1);
  ps += __shfl_xor(ps, 2); pd += __shfl_xor(pd, 2);
  ps += __shfl_xor(ps, 4); pd += __shfl_xor(pd, 4);
  if ((lane & 7) == 0) {
    als[(size_t)wid * 8 + (lane >> 3)] = ps;
    ald[(size_t)wid * 8 + (lane >> 3)] = pd;
  }
}

// ---------------- single-pass online-softmax GAT aggregation (bf16 gather) ----------------
__global__ __launch_bounds__(256) void k_agg(const unsigned short* __restrict__ h,
                                             const float* __restrict__ als,
                                             const float* __restrict__ ald,
                                             const int* __restrict__ ptr,
                                             const int* __restrict__ srcs,
                                             const float* __restrict__ bias,
                                             float* __restrict__ out, int n) {
  int wid = (blockIdx.x * 256 + threadIdx.x) >> 6;
  int lane = threadIdx.x & 63;
  if (wid >= n) return;
  const int beg = ptr[wid], end = ptr[wid + 1];
  const int hme = lane >> 3;
  const float adh = ald[(size_t)wid * 8 + hme];
  float m = -1e30f, s = 0.f;
  float ax = 0.f, ay = 0.f, az = 0.f, aw = 0.f;
  for (int j = beg; j < end; ++j) {
    int sN = srcs[j];
    float lg = lrelu(als[(size_t)sN * 8 + hme] + adh, 0.2f);
    float mn = fmaxf(m, lg);
    float c = __expf(m - mn);
    float wt = __expf(lg - mn);
    m = mn;
    s = s * c + wt;
    ushort4 hv = *(const ushort4*)(h + (size_t)sN * 256 + lane * 4);
    ax = ax * c + wt * b2f(hv.x);
    ay = ay * c + wt * b2f(hv.y);
    az = az * c + wt * b2f(hv.z);
    aw = aw * c + wt * b2f(hv.w);
  }
  const float inv = 1.f / (s + 1e-16f);
  float4 bv = *(const float4*)(bias + lane * 4);
  float4 o;
  o.x = ax * inv + bv.x;
  o.y = ay * inv + bv.y;
  o.z = az * inv + bv.z;
  o.w = aw * inv + bv.w;
  *(float4*)(out + (size_t)wid * 256 + lane * 4) = o;
}

// ---------------- BatchNorm stats + fused apply/LeakyReLU(+residual) ----------------
__global__ __launch_bounds__(256) void k_bnstats(const float* __restrict__ x,
                                                 float* __restrict__ stats, int n) {
  int c = threadIdx.x;
  float sum = 0.f, sq = 0.f;
  for (int r = blockIdx.x; r < n; r += gridDim.x) {
    float v = x[(size_t)r * 256 + c];
    sum += v;
    sq += v * v;
  }
  atomicAdd(&stats[c], sum);
  atomicAdd(&stats[256 + c], sq);
}

__global__ __launch_bounds__(256) void k_bnact(float* __restrict__ x,
                                               const float* __restrict__ stats,
                                               const float* __restrict__ ga,
                                               const float* __restrict__ be,
                                               const float* __restrict__ res,
                                               unsigned short* __restrict__ xb,
                                               int writef32, int n) {
  const float invn = 1.f / (float)n;
  const int tot4 = n * 64;
  for (int t = blockIdx.x * 256 + threadIdx.x; t < tot4; t += gridDim.x * 256) {
    int i0 = t * 4;
    int c = i0 & 255;
    float4 xv = *(const float4*)(x + i0);
    float4 sm = *(const float4*)(stats + c);
    float4 sq = *(const float4*)(stats + 256 + c);
    float4 gv = *(const float4*)(ga + c);
    float4 bev = *(const float4*)(be + c);
    float o0, o1, o2, o3, mu, var, sc;
    mu = sm.x * invn; var = sq.x * invn - mu * mu; sc = gv.x * rsqrtf(var + 1e-5f);
    o0 = (xv.x - mu) * sc + bev.x; o0 = o0 >= 0.f ? o0 : 0.01f * o0;
    mu = sm.y * invn; var = sq.y * invn - mu * mu; sc = gv.y * rsqrtf(var + 1e-5f);
    o1 = (xv.y - mu) * sc + bev.y; o1 = o1 >= 0.f ? o1 : 0.01f * o1;
    mu = sm.z * invn; var = sq.z * invn - mu * mu; sc = gv.z * rsqrtf(var + 1e-5f);
    o2 = (xv.z - mu) * sc + bev.z; o2 = o2 >= 0.f ? o2 : 0.01f * o2;
    mu = sm.w * invn; var = sq.w * invn - mu * mu; sc = gv.w * rsqrtf(var + 1e-5f);
    o3 = (xv.w - mu) * sc + bev.w; o3 = o3 >= 0.f ? o3 : 0.01f * o3;
    if (res) {
      float4 rv = *(const float4*)(res + i0);
      o0 += rv.x; o1 += rv.y; o2 += rv.z; o3 += rv.w;
    }
    if (writef32) *(float4*)(x + i0) = make_float4(o0, o1, o2, o3);
    ushort4 ob;
    ob.x = f2b(o0); ob.y = f2b(o1); ob.z = f2b(o2); ob.w = f2b(o3);
    *(ushort4*)(xb + i0) = ob;
  }
}

// ---------------- layer 3: h3 = x @ W3 (256->4) + attention coefficients ----------------
__global__ __launch_bounds__(256) void k_gemm3(const unsigned short* __restrict__ x,
                                               const float* __restrict__ W3,
                                               const float* __restrict__ as3,
                                               const float* __restrict__ ad3,
                                               float* __restrict__ h3,
                                               float* __restrict__ als3,
                                               float* __restrict__ ald3, int n) {
  int wid = (blockIdx.x * 256 + threadIdx.x) >> 6;
  int lane = threadIdx.x & 63;
  if (wid >= n) return;
  ushort4 xu = *(const ushort4*)(x + (size_t)wid * 256 + lane * 4);
  float x0 = b2f(xu.x), x1 = b2f(xu.y), x2 = b2f(xu.z), x3 = b2f(xu.w);
  const float4* Wp = (const float4*)W3 + lane * 4;
  float4 w0 = Wp[0], w1 = Wp[1], w2 = Wp[2], w3 = Wp[3];
  float a0 = x0 * w0.x + x1 * w1.x + x2 * w2.x + x3 * w3.x;
  float a1 = x0 * w0.y + x1 * w1.y + x2 * w2.y + x3 * w3.y;
  float a2 = x0 * w0.z + x1 * w1.z + x2 * w2.z + x3 * w3.z;
  float a3 = x0 * w0.w + x1 * w1.w + x2 * w2.w + x3 * w3.w;
#pragma unroll
  for (int off = 1; off < 64; off <<= 1) {
    a0 += __shfl_xor(a0, off);
    a1 += __shfl_xor(a1, off);
    a2 += __shfl_xor(a2, off);
    a3 += __shfl_xor(a3, off);
  }
  if (lane == 0) {
    *(float4*)(h3 + (size_t)wid * 4) = make_float4(a0, a1, a2, a3);
    als3[wid] = a0 * as3[0] + a1 * as3[1] + a2 * as3[2] + a3 * as3[3];
    ald3[wid] = a0 * ad3[0] + a1 * ad3[1] + a2 * ad3[2] + a3 * ad3[3];
  }
}

// ---------------- layer 3 aggregation (1 head, 4 channels) -> d_out ----------------
__global__ __launch_bounds__(256) void k_agg3(const float* __restrict__ h3,
                                              const float* __restrict__ als3,
                                              const float* __restrict__ ald3,
                                              const int* __restrict__ ptr,
                                              const int* __restrict__ srcs,
                                              const float* __restrict__ b3,
                                              float* __restrict__ out, int n) {
  int wid = (blockIdx.x * 256 + threadIdx.x) >> 6;
  int lane = threadIdx.x & 63;
  if (wid >= n) return;
  const int beg = ptr[wid], end = ptr[wid + 1];
  const float aldh = ald3[wid];
  float m = -1e30f;
  for (int j = beg + lane; j < end; j += 64)
    m = fmaxf(m, lrelu(als3[srcs[j]] + aldh, 0.2f));
#pragma unroll
  for (int off = 1; off < 64; off <<= 1) m = fmaxf(m, __shfl_xor(m, off));
  float s = 0.f, a0 = 0.f, a1 = 0.f, a2 = 0.f, a3 = 0.f;
  for (int j = beg + lane; j < end; j += 64) {
    int sN = srcs[j];
    float wgt = __expf(lrelu(als3[sN] + aldh, 0.2f) - m);
    s += wgt;
    float4 hv = *(const float4*)(h3 + (size_t)sN * 4);
    a0 += wgt * hv.x;
    a1 += wgt * hv.y;
    a2 += wgt * hv.z;
    a3 += wgt * hv.w;
  }
#pragma unroll
  for (int off = 1; off < 64; off <<= 1) {
    s += __shfl_xor(s, off);
    a0 += __shfl_xor(a0, off);
    a1 += __shfl_xor(a1, off);
    a2 += __shfl_xor(a2, off);
    a3 += __shfl_xor(a3, off);
  }
  if (lane == 0) {
    float inv = 1.f / (s + 1e-16f);
    out[(size_t)wid * 4 + 0] = a0 * inv + b3[0];
    out[(size_t)wid * 4 + 1] = a1 * inv + b3[1];
    out[(size_t)wid * 4 + 2] = a2 * inv + b3[2];
    out[(size_t)wid * 4 + 3] = a3 * inv + b3[3];
  }
}

extern "C" void kernel_launch(void* const* d_in, const int* in_sizes, int n_in,
                              void* d_out, int out_size, void* d_ws, size_t ws_size,
                              hipStream_t stream) {
  const float* x   = (const float*)d_in[0];
  const int*   ei  = (const int*)d_in[1];
  const float* W1  = (const float*)d_in[2];
  const float* as1 = (const float*)d_in[3];
  const float* ad1 = (const float*)d_in[4];
  const float* b1  = (const float*)d_in[5];
  const float* ga1 = (const float*)d_in[6];
  const float* be1 = (const float*)d_in[7];
  const float* W2  = (const float*)d_in[8];
  const float* as2 = (const float*)d_in[9];
  const float* ad2 = (const float*)d_in[10];
  const float* b2  = (const float*)d_in[11];
  const float* ga2 = (const float*)d_in[12];
  const float* be2 = (const float*)d_in[13];
  const float* W3  = (const float*)d_in[14];
  const float* as3 = (const float*)d_in[15];
  const float* ad3 = (const float*)d_in[16];
  const float* b3  = (const float*)d_in[17];

  const int N = in_sizes[0] / 128;
  const int E = in_sizes[1] / 2;
  const int ET = E + N;
  float* out = (float*)d_out;

  char* w = (char*)d_ws;
  auto alloc = [&](size_t bytes) -> void* {
    void* p = (void*)w;
    w += (bytes + 255) & ~(size_t)255;
    return p;
  };
  int* ptr              = (int*)alloc((size_t)(N + 1) * 4);
  int* fill             = (int*)alloc((size_t)N * 4);
  int* cnt              = (int*)alloc((size_t)N * 4);
  int* bsum             = (int*)alloc(64 * 4);
  int* boff             = (int*)alloc(64 * 4);
  int* srcs             = (int*)alloc((size_t)ET * 4);
  unsigned short* hbuf  = (unsigned short*)alloc((size_t)N * 256 * 2);
  float* agg1           = (float*)alloc((size_t)N * 256 * 4);
  unsigned short* a2b   = (unsigned short*)alloc((size_t)N * 256 * 2);
  float* als            = (float*)alloc((size_t)N * 8 * 4);
  float* ald            = (float*)alloc((size_t)N * 8 * 4);
  float* h3             = (float*)alloc((size_t)N * 4 * 4);
  float* als3           = (float*)alloc((size_t)N * 4);
  float* ald3           = (float*)alloc((size_t)N * 4);
  float* stats          = (float*)alloc(1024 * 4);
  char* uni             = (char*)alloc((size_t)N * 256 * 4);
  unsigned short* xb    = (unsigned short*)uni;
  unsigned short* w1t   = (unsigned short*)(uni + (size_t)N * 128 * 2);
  unsigned short* w2t   = w1t + 256 * 128;
  unsigned short* a1b   = w2t + 256 * 256;
  float* agg2           = (float*)uni;

  const int* esrc = ei;
  const int* edst = ei + E;

  hipMemsetAsync(stats, 0, 1024 * 4, stream);

  // CSR (shared by all three layers) — parallel 3-phase scan
  const int B = (N + 1023) / 1024;  // 49 for N=50000, must be <= 64
  k_init_cnt<<<(N + 255) / 256, 256, 0, stream>>>(cnt, N);
  k_hist<<<(E + 255) / 256, 256, 0, stream>>>(edst, E, cnt);
  k_bsum<<<B, 256, 0, stream>>>(cnt, bsum, N);
  k_scanb<<<1, 64, 0, stream>>>(bsum, boff, ptr + N, B);
  k_scanl<<<B, 256, 0, stream>>>(cnt, boff, ptr, fill, N);
  k_scatter<<<(ET + 255) / 256, 256, 0, stream>>>(esrc, edst, E, N, fill, srcs);

  // bf16 conversions
  k_f2b<<<((N * 32) + 255) / 256, 256, 0, stream>>>(x, xb, N * 32);
  k_cvtT<<<(256 * 128 + 255) / 256, 256, 0, stream>>>(W1, w1t, 128, 256);
  k_cvtT<<<(256 * 256 + 255) / 256, 256, 0, stream>>>(W2, w2t, 256, 256);

  const dim3 gemm_grid((N + 127) / 128, 2);
  const int wblocks = (N + 3) / 4;

  // layer 1
  k_mfma<<<gemm_grid, 256, 0, stream>>>(xb, w1t, hbuf, N, 256, 128);
  k_attn<<<wblocks, 256, 0, stream>>>(hbuf, as1, ad1, als, ald, N);
  k_agg<<<wblocks, 256, 0, stream>>>(hbuf, als, ald, ptr, srcs, b1, agg1, N);
  k_bnstats<<<512, 256, 0, stream>>>(agg1, stats, N);
  k_bnact<<<2048, 256, 0, stream>>>(agg1, stats, ga1, be1, nullptr, a1b, 1, N);

  // layer 2 (+ residual)
  k_mfma<<<gemm_grid, 256, 0, stream>>>(a1b, w2t, hbuf, N, 256, 256);
  k_attn<<<wblocks, 256, 0, stream>>>(hbuf, as2, ad2, als, ald, N);
  k_agg<<<wblocks, 256, 0, stream>>>(hbuf, als, ald, ptr, srcs, b2, agg2, N);
  k_bnstats<<<512, 256, 0, stream>>>(agg2, stats + 512, N);
  k_bnact<<<2048, 256, 0, stream>>>(agg2, stats + 512, ga2, be2, agg1, a2b, 0, N);

  // layer 3 -> output
  k_gemm3<<<wblocks, 256, 0, stream>>>(a2b, W3, as3, ad3, h3, als3, ald3, N);
  k_agg3<<<wblocks, 256, 0, stream>>>(h3, als3, ald3, ptr, srcs, b3, out, N);
}